// Round 3
// baseline (679.983 us; speedup 1.0000x reference)
//
#include <hip/hip_runtime.h>

// LIF constants folded:
//   i' = 0.8*s + x ;  v' = 0.9*m + 0.1*i' ;  spike = v' >= 1.0 ; 2x2 max-pool.
//
// R3: persistent grid-stride loop (m13 copy-bench structure) with explicit
// next-iteration prefetch. 2048 blocks x 256 thr, 16 iters/thread, 6 loads
// per iter, rotating prefetch registers -> ~12 loads continuously in flight,
// no full vmcnt drain per work item, 32x fewer wave launches.

constexpr int B = 16, C = 64, H = 256, W = 256;
constexpr int W4  = W / 4;                 // 64 float4 groups per input row
constexpr int TOTAL = (B * C * H / 2) * W4; // 8,388,608 work items (1 item = 2x4 input block)
constexpr int BLOCK = 256;
constexpr int GRID = 2048;                 // 8 blocks/CU
constexpr int STRIDE = BLOCK * GRID;       // 524,288
constexpr int ITERS = TOTAL / STRIDE;      // 16 (exact)

__device__ __forceinline__ float lif_v(float m, float s, float x) {
    return fmaf(0.9f, m, 0.1f * fmaf(0.8f, s, x));
}

__device__ __forceinline__ int in_base(int t) {
    // work item t -> float4 index of input row 2*(t>>6), column group (t&63)
    return ((t >> 6) * 2) * W4 + (t & 63);
}

__global__ __launch_bounds__(256) void lif_pool_kernel(
    const float4* __restrict__ x,
    const float4* __restrict__ m,
    const float4* __restrict__ s,
    float2* __restrict__ out)
{
    int t = blockIdx.x * BLOCK + threadIdx.x;

    // Prefetch iteration 0.
    int ia = in_base(t);
    float4 X0 = x[ia], X1 = x[ia + W4];
    float4 M0 = m[ia], M1 = m[ia + W4];
    float4 S0 = s[ia], S1 = s[ia + W4];

#pragma unroll
    for (int i = 0; i < ITERS; ++i) {
        float4 nX0, nX1, nM0, nM1, nS0, nS1;
        int tn = t + STRIDE;
        if (i + 1 < ITERS) {  // statically resolved under full unroll
            int ib = in_base(tn);
            nX0 = x[ib]; nX1 = x[ib + W4];
            nM0 = m[ib]; nM1 = m[ib + W4];
            nS0 = s[ib]; nS1 = s[ib + W4];
        }

        // Compute current item.
        float a0 = lif_v(M0.x, S0.x, X0.x), a1 = lif_v(M0.y, S0.y, X0.y);
        float a2 = lif_v(M0.z, S0.z, X0.z), a3 = lif_v(M0.w, S0.w, X0.w);
        float b0 = lif_v(M1.x, S1.x, X1.x), b1 = lif_v(M1.y, S1.y, X1.y);
        float b2 = lif_v(M1.z, S1.z, X1.z), b3 = lif_v(M1.w, S1.w, X1.w);
        float w0 = fmaxf(fmaxf(a0, a1), fmaxf(b0, b1));
        float w1 = fmaxf(fmaxf(a2, a3), fmaxf(b2, b3));
        float2 o;
        o.x = (w0 >= 1.0f) ? 1.0f : 0.0f;
        o.y = (w1 >= 1.0f) ? 1.0f : 0.0f;
        out[t] = o;  // out item index == t (orow*64 + g)

        // Rotate pipeline.
        X0 = nX0; X1 = nX1; M0 = nM0; M1 = nM1; S0 = nS0; S1 = nS1;
        t = tn;
    }
}

extern "C" void kernel_launch(void* const* d_in, const int* in_sizes, int n_in,
                              void* d_out, int out_size, void* d_ws, size_t ws_size,
                              hipStream_t stream) {
    const float4* x = (const float4*)d_in[0];  // input_signal
    const float4* m = (const float4*)d_in[1];  // membrane
    const float4* s = (const float4*)d_in[2];  // synaptic
    float2* out = (float2*)d_out;

    lif_pool_kernel<<<GRID, BLOCK, 0, stream>>>(x, m, s, out);
}

// Round 4
// 668.039 us; speedup vs baseline: 1.0179x; 1.0179x over previous
//
#include <hip/hip_runtime.h>

// LIF constants folded:
//   i' = 0.8*s + x ;  v' = 0.9*m + 0.1*i' ;  spike = v' >= 1.0 ; 2x2 max-pool.
//
// R4: R1 structure (best so far, 214 us) + XCD-contiguous block swizzle.
// Blocks are dispatched round-robin across 8 XCDs; remap blockIdx so each
// XCD processes a contiguous 1/8 slab of the arrays (localized L2 fills /
// DRAM channel traffic per XCD) instead of an 8-way-interleaved stride.

constexpr int B = 16, C = 64, H = 256, W = 256;
constexpr int OW = W / 2;                        // 128
constexpr int NROWS = B * C * H;                 // input rows
constexpr int NTHREADS = (NROWS / 2) * (OW / 2); // 1 thread = 2 output px = 2x4 input block
constexpr int BLOCK = 256;
constexpr int GRID = NTHREADS / BLOCK;           // 32768, exact
constexpr int NXCD = 8;
constexpr int PER_XCD = GRID / NXCD;             // 4096

__global__ __launch_bounds__(256) void lif_pool_kernel(
    const float4* __restrict__ x,
    const float4* __restrict__ m,
    const float4* __restrict__ s,
    float2* __restrict__ out)
{
    // Swizzle: dispatch-order bid -> (bid%8)'th XCD gets contiguous slab.
    int bid = blockIdx.x;
    int sb  = (bid & (NXCD - 1)) * PER_XCD + (bid >> 3);

    int t = sb * BLOCK + threadIdx.x;

    int orow = t >> 6;   // output row index
    int g    = t & 63;   // float4 column group within the row-pair

    int i0 = (2 * orow) * (W / 4) + g;
    int i1 = i0 + (W / 4);

    float4 x0 = x[i0], x1 = x[i1];
    float4 m0 = m[i0], m1 = m[i1];
    float4 s0 = s[i0], s1 = s[i1];

    float v00 = fmaf(0.9f, m0.x, 0.1f * fmaf(0.8f, s0.x, x0.x));
    float v01 = fmaf(0.9f, m0.y, 0.1f * fmaf(0.8f, s0.y, x0.y));
    float v02 = fmaf(0.9f, m0.z, 0.1f * fmaf(0.8f, s0.z, x0.z));
    float v03 = fmaf(0.9f, m0.w, 0.1f * fmaf(0.8f, s0.w, x0.w));
    float v10 = fmaf(0.9f, m1.x, 0.1f * fmaf(0.8f, s1.x, x1.x));
    float v11 = fmaf(0.9f, m1.y, 0.1f * fmaf(0.8f, s1.y, x1.y));
    float v12 = fmaf(0.9f, m1.z, 0.1f * fmaf(0.8f, s1.z, x1.z));
    float v13 = fmaf(0.9f, m1.w, 0.1f * fmaf(0.8f, s1.w, x1.w));

    float w0 = fmaxf(fmaxf(v00, v01), fmaxf(v10, v11));
    float w1 = fmaxf(fmaxf(v02, v03), fmaxf(v12, v13));

    float2 o;
    o.x = (w0 >= 1.0f) ? 1.0f : 0.0f;
    o.y = (w1 >= 1.0f) ? 1.0f : 0.0f;

    out[orow * (OW / 2) + g] = o;
}

extern "C" void kernel_launch(void* const* d_in, const int* in_sizes, int n_in,
                              void* d_out, int out_size, void* d_ws, size_t ws_size,
                              hipStream_t stream) {
    const float4* x = (const float4*)d_in[0];  // input_signal
    const float4* m = (const float4*)d_in[1];  // membrane
    const float4* s = (const float4*)d_in[2];  // synaptic
    float2* out = (float2*)d_out;

    lif_pool_kernel<<<GRID, BLOCK, 0, stream>>>(x, m, s, out);
}